// Round 6
// baseline (451.413 us; speedup 1.0000x reference)
//
#include <hip/hip_runtime.h>
#include <math.h>

// N = 20000, E = 640000, IN_DIM = HID = 128, OUT = 64
// Persistent megakernel (240 blocks x 512 thr, 1 block/CU), software grid
// barrier (validated pattern: r4 bench's cross-block acquire/release spin).
// Activations bf16, accumulation fp32 via MFMA 16x16x32.

typedef __attribute__((ext_vector_type(8))) short short8;
typedef __attribute__((ext_vector_type(4))) float floatx4;

__device__ __forceinline__ unsigned short f2b(float f) {
    unsigned u = __float_as_uint(f);
    return (unsigned short)((u + 0x7fffu + ((u >> 16) & 1u)) >> 16);
}
__device__ __forceinline__ unsigned pack2(float a, float b) {
    return (unsigned)f2b(a) | ((unsigned)f2b(b) << 16);
}
__device__ __forceinline__ float b2f_lo(unsigned v) { return __uint_as_float(v << 16); }
__device__ __forceinline__ float b2f_hi(unsigned v) { return __uint_as_float(v & 0xffff0000u); }
__device__ __forceinline__ floatx4 MFMA(short8 a, short8 b, floatx4 c) {
    return __builtin_amdgcn_mfma_f32_16x16x32_bf16(a, b, c, 0, 0, 0);
}
__device__ __forceinline__ float gelu_exact(float x) {
    return 0.5f * x * (1.0f + erff(x * 0.70710678118654752440f));
}
#define FRAG(P, ct, ks, lane) (*(const short8*)((P) + (((((ct)*4 + (ks))*64) + (lane)) << 3)))

// ---- software grid barrier: slot padded to its own cache line ----
__device__ __forceinline__ void gbar(int* bar, int slot, int nblk) {
    __syncthreads();
    if (threadIdx.x == 0) {
        __threadfence();  // agent-scope release of all prior writes
        __hip_atomic_fetch_add(&bar[slot * 32], 1, __ATOMIC_RELEASE,
                               __HIP_MEMORY_SCOPE_AGENT);
        while (__hip_atomic_load(&bar[slot * 32], __ATOMIC_ACQUIRE,
                                 __HIP_MEMORY_SCOPE_AGENT) < nblk) {
            __builtin_amdgcn_s_sleep(1);
        }
    }
    __syncthreads();
}

__device__ __forceinline__ void pack_one(const float* W, unsigned short* P, int NC, int base) {
    int l  = base & 63;
    int ks = (base >> 6) & 3;
    int ct = base >> 8;
    int n  = ct * 16 + (l & 15);
    int k0 = ks * 32 + ((l >> 4) << 3);
    short8 v;
    #pragma unroll
    for (int j = 0; j < 8; j++) v[j] = (short)f2b(W[(size_t)(k0 + j) * NC + n]);
    *(short8*)(P + ((size_t)base << 3)) = v;
}

__device__ __forceinline__ void accum8(float* acc, uint4 q) {
    acc[0] += b2f_lo(q.x); acc[1] += b2f_hi(q.x);
    acc[2] += b2f_lo(q.y); acc[3] += b2f_hi(q.y);
    acc[4] += b2f_lo(q.z); acc[5] += b2f_hi(q.z);
    acc[6] += b2f_lo(q.w); acc[7] += b2f_hi(q.w);
}
__device__ __forceinline__ void step16(const uint4* Xq, const int* __restrict__ col,
                                       int jb, int g, int t, float* acc) {
    int s0 = col[jb + g];
    int s1 = col[jb + 4 + g];
    int s2 = col[jb + 8 + g];
    int s3 = col[jb + 12 + g];
    uint4 q0 = Xq[(size_t)s0 * 16 + t];
    uint4 q1 = Xq[(size_t)s1 * 16 + t];
    uint4 q2 = Xq[(size_t)s2 * 16 + t];
    uint4 q3 = Xq[(size_t)s3 * 16 + t];
    accum8(acc, q0); accum8(acc, q1); accum8(acc, q2); accum8(acc, q3);
}
__device__ __forceinline__ void tail4(const uint4* Xq, const int* __restrict__ col,
                                      int jb, int end, int g, int t, float* acc) {
    for (int j = jb + g; j < end; j += 4) {
        int s = col[j];
        uint4 q = Xq[(size_t)s * 16 + t];
        accum8(acc, q);
    }
}
__device__ __forceinline__ void store_gcn(unsigned short* Y, const uint4* Xq,
                                          const float* dinv, const float* bias,
                                          int w, int t, float* acc) {
    uint4 q = Xq[(size_t)w * 16 + t];   // self loop (row pre-scaled by dinv[w])
    accum8(acc, q);
    float dw = dinv[w];
    float4 b0 = *(const float4*)(bias + t * 8);
    float4 b1 = *(const float4*)(bias + t * 8 + 4);
    uint4 r;
    r.x = pack2(fmaxf(fmaf(acc[0], dw, b0.x), 0.f), fmaxf(fmaf(acc[1], dw, b0.y), 0.f));
    r.y = pack2(fmaxf(fmaf(acc[2], dw, b0.z), 0.f), fmaxf(fmaf(acc[3], dw, b0.w), 0.f));
    r.z = pack2(fmaxf(fmaf(acc[4], dw, b1.x), 0.f), fmaxf(fmaf(acc[5], dw, b1.y), 0.f));
    r.w = pack2(fmaxf(fmaf(acc[6], dw, b1.z), 0.f), fmaxf(fmaf(acc[7], dw, b1.w), 0.f));
    ((uint4*)Y)[(size_t)w * 16 + t] = r;
}
__device__ __forceinline__ void store_mean(unsigned short* Y, int w, int t, int deg, float* acc) {
    float rc = 1.0f / (float)(deg > 0 ? deg : 1);
    uint4 r;
    r.x = pack2(acc[0] * rc, acc[1] * rc);
    r.y = pack2(acc[2] * rc, acc[3] * rc);
    r.z = pack2(acc[4] * rc, acc[5] * rc);
    r.w = pack2(acc[6] * rc, acc[7] * rc);
    ((uint4*)Y)[(size_t)w * 16 + t] = r;
}

// Two adjacent nodes per wave: 8 independent 16B gathers in flight.
__device__ void agg_phase(bool gcn, const unsigned short* X, const int* __restrict__ row_ptr,
                          const int* __restrict__ col, const float* __restrict__ dinv,
                          const float* __restrict__ bias, unsigned short* Y,
                          int N, int wi, int nw, int lane)
{
    int g = lane >> 4, t = lane & 15;
    const uint4* Xq = (const uint4*)X;
    for (int pw = wi; pw * 2 < N; pw += nw) {
        int w0 = pw * 2, w1 = w0 + 1;
        int beg0 = row_ptr[w0];
        int mid  = row_ptr[w1];
        int end1 = row_ptr[w1 + 1];
        float acc0[8] = {0.f,0.f,0.f,0.f,0.f,0.f,0.f,0.f};
        float acc1[8] = {0.f,0.f,0.f,0.f,0.f,0.f,0.f,0.f};
        int jb0 = beg0, jb1 = mid;
        while (jb0 + 16 <= mid && jb1 + 16 <= end1) {
            step16(Xq, col, jb0, g, t, acc0);
            step16(Xq, col, jb1, g, t, acc1);
            jb0 += 16; jb1 += 16;
        }
        while (jb0 + 16 <= mid)  { step16(Xq, col, jb0, g, t, acc0); jb0 += 16; }
        while (jb1 + 16 <= end1) { step16(Xq, col, jb1, g, t, acc1); jb1 += 16; }
        tail4(Xq, col, jb0, mid,  g, t, acc0);
        tail4(Xq, col, jb1, end1, g, t, acc1);
        #pragma unroll
        for (int i = 0; i < 8; i++) {
            acc0[i] += __shfl_xor(acc0[i], 16); acc0[i] += __shfl_xor(acc0[i], 32);
            acc1[i] += __shfl_xor(acc1[i], 16); acc1[i] += __shfl_xor(acc1[i], 32);
        }
        if (gcn) {
            if (g == 0)      store_gcn(Y, Xq, dinv, bias, w0, t, acc0);
            else if (g == 1) store_gcn(Y, Xq, dinv, bias, w1, t, acc1);
        } else {
            if (g == 0)      store_mean(Y, w0, t, mid - beg0, acc0);
            else if (g == 1) store_mean(Y, w1, t, end1 - mid, acc1);
        }
    }
}

__global__ __launch_bounds__(512, 2) void mega_kernel(
    const float* __restrict__ feat, const int* __restrict__ eidx,
    const float* __restrict__ Wg,  const float* __restrict__ bg,
    const float* __restrict__ Wsl, const float* __restrict__ bsl,
    const float* __restrict__ Wsr,
    const float* __restrict__ W1,  const float* __restrict__ b1,
    const float* __restrict__ W2,  const float* __restrict__ b2,
    const float* __restrict__ W3,  const float* __restrict__ b3,
    const float* __restrict__ Wv,  const float* __restrict__ bv,
    int* bar, int* cnt, int* rank, int* row_ptr, float* dinv, int* col, int* gsums,
    unsigned short* xs, unsigned short* h1, unsigned short* mean,
    unsigned short* Pg, unsigned short* Psl, unsigned short* Psr,
    unsigned short* P1p, unsigned short* P2p, unsigned short* P3p,
    float* means, float* values, int N, int E)
{
    const int tid  = threadIdx.x;
    const int nblk = gridDim.x;
    const int gtid = blockIdx.x * 512 + tid;
    const int GT   = nblk * 512;
    const int lane = tid & 63;
    const int widx = tid >> 6;
    const int wi   = gtid >> 6;
    const int nw   = GT >> 6;

    __shared__ union { int gs[256]; unsigned short mlp[8 * 2176]; } sm;
    __shared__ int loc[96];
    __shared__ int red[512];

    // ---- P0: pack weights to MFMA fragment order (cnt zeroed by host memset)
    for (int t0 = gtid; t0 < 11264; t0 += GT) {
        if      (t0 < 2048)  pack_one(Wg,  Pg,  128, t0);
        else if (t0 < 4096)  pack_one(Wsl, Psl, 128, t0 - 2048);
        else if (t0 < 6144)  pack_one(Wsr, Psr, 128, t0 - 4096);
        else if (t0 < 8192)  pack_one(W1,  P1p, 128, t0 - 6144);
        else if (t0 < 10240) pack_one(W2,  P2p, 128, t0 - 8192);
        else                 pack_one(W3,  P3p, 64,  t0 - 10240);
    }
    gbar(bar, 0, nblk);

    // ---- P1: degree count + per-edge rank ----
    for (int e = gtid; e < E; e += GT)
        rank[e] = atomicAdd(&cnt[eidx[E + e]], 1);
    gbar(bar, 1, nblk);

    // ---- P2: block-local exclusive prefix of counts ----
    const int NPB = (N + nblk - 1) / nblk;   // 84 @ nblk=240
    const int n0  = blockIdx.x * NPB;
    int ncount = N - n0; if (ncount > NPB) ncount = NPB; if (ncount < 0) ncount = 0;
    if (tid < ncount) loc[tid] = cnt[n0 + tid];
    __syncthreads();
    if (tid == 0) {
        int s = 0;
        for (int i = 0; i < ncount; i++) { int v = loc[i]; loc[i] = s; s += v; }
        gsums[blockIdx.x] = s;
    }
    gbar(bar, 2, nblk);

    // ---- P3: absolute row_ptr + dinv ----
    for (int i = tid; i < nblk; i += 512) sm.gs[i] = gsums[i];
    __syncthreads();
    {
        int p = 0;
        for (int j = tid; j < (int)blockIdx.x; j += 512) p += sm.gs[j];
        red[tid] = p;
        __syncthreads();
        for (int s = 256; s > 0; s >>= 1) {
            if (tid < s) red[tid] += red[tid + s];
            __syncthreads();
        }
    }
    const int boff = red[0];
    for (int i = tid; i < ncount; i += 512) {
        row_ptr[n0 + i] = boff + loc[i];
        dinv[n0 + i] = rsqrtf((float)(cnt[n0 + i] + 1));
    }
    if (gtid == 0) row_ptr[N] = E;
    gbar(bar, 3, nblk);

    // ---- P4: CSR fill (atomic-free via rank)  +  GCN GEMM -> xs (dinv-scaled)
    for (int e = gtid; e < E; e += GT) {
        int d = eidx[E + e];
        col[row_ptr[d] + rank[e]] = eidx[e];
    }
    {
        const int m = lane & 15, quad = lane >> 4;
        const int T2 = (N / 16) * 2;
        for (int w = wi; w < T2; w += nw) {
            int rt = w >> 1, ch = w & 1;
            const float* arow = feat + (size_t)(rt * 16 + m) * 128;
            short8 a[4];
            #pragma unroll
            for (int ks = 0; ks < 4; ks++) {
                float4 f0 = *(const float4*)(arow + ks * 32 + quad * 8);
                float4 f1 = *(const float4*)(arow + ks * 32 + quad * 8 + 4);
                short8 s;
                s[0] = (short)f2b(f0.x); s[1] = (short)f2b(f0.y);
                s[2] = (short)f2b(f0.z); s[3] = (short)f2b(f0.w);
                s[4] = (short)f2b(f1.x); s[5] = (short)f2b(f1.y);
                s[6] = (short)f2b(f1.z); s[7] = (short)f2b(f1.w);
                a[ks] = s;
            }
            float dvr[4];
            #pragma unroll
            for (int reg = 0; reg < 4; reg++) dvr[reg] = dinv[rt * 16 + quad * 4 + reg];
            #pragma unroll
            for (int ct = 0; ct < 4; ct++) {
                floatx4 acc = {0.f, 0.f, 0.f, 0.f};
                #pragma unroll
                for (int ks = 0; ks < 4; ks++)
                    acc = MFMA(a[ks], FRAG(Pg, ch * 4 + ct, ks, lane), acc);
                #pragma unroll
                for (int reg = 0; reg < 4; reg++)
                    xs[(size_t)(rt * 16 + quad * 4 + reg) * 128 + (ch * 4 + ct) * 16 + m] =
                        f2b(acc[reg] * dvr[reg]);
            }
        }
    }
    gbar(bar, 4, nblk);

    // ---- P5: GCN aggregation -> h1 ----
    agg_phase(true, xs, row_ptr, col, dinv, bg, h1, N, wi, nw, lane);
    gbar(bar, 5, nblk);

    // ---- P6: SAGE mean aggregation -> mean ----
    agg_phase(false, h1, row_ptr, col, dinv, nullptr, mean, N, wi, nw, lane);
    gbar(bar, 6, nblk);

    // ---- P7: SAGE linear + policy MLP + value head ----
    {
        unsigned short* zt = &sm.mlp[widx * 2176];
        const int m = lane & 15, quad = lane >> 4;
        const int M16 = N / 16;
        for (int w = wi; w < M16; w += nw) {
            int r0 = w * 16;
            short8 am[4], ar[4];
            #pragma unroll
            for (int ks = 0; ks < 4; ks++) {
                am[ks] = *(const short8*)(mean + (size_t)(r0 + m) * 128 + ks * 32 + quad * 8);
                ar[ks] = *(const short8*)(h1   + (size_t)(r0 + m) * 128 + ks * 32 + quad * 8);
            }
            float vpart[4] = {0.f, 0.f, 0.f, 0.f};
            #pragma unroll
            for (int ct = 0; ct < 8; ct++) {
                floatx4 acc = {0.f, 0.f, 0.f, 0.f};
                #pragma unroll
                for (int ks = 0; ks < 4; ks++) acc = MFMA(am[ks], FRAG(Psl, ct, ks, lane), acc);
                #pragma unroll
                for (int ks = 0; ks < 4; ks++) acc = MFMA(ar[ks], FRAG(Psr, ct, ks, lane), acc);
                float bb = bsl[ct * 16 + m];
                float wv = Wv[ct * 16 + m];
                #pragma unroll
                for (int reg = 0; reg < 4; reg++) {
                    float o = fmaxf(acc[reg] + bb, 0.f);
                    vpart[reg] = fmaf(o, wv, vpart[reg]);
                    zt[(quad * 4 + reg) * 136 + ct * 16 + m] = f2b(o);
                }
            }
            #pragma unroll
            for (int off = 1; off <= 8; off <<= 1) {
                #pragma unroll
                for (int reg = 0; reg < 4; reg++)
                    vpart[reg] += __shfl_xor(vpart[reg], off);
            }
            if (m == 0) {
                float bvv = bv[0];
                #pragma unroll
                for (int reg = 0; reg < 4; reg++)
                    values[r0 + quad * 4 + reg] = vpart[reg] + bvv;
            }
            short8 a1[4];
            #pragma unroll
            for (int ks = 0; ks < 4; ks++)
                a1[ks] = *(const short8*)(zt + m * 136 + ks * 32 + quad * 8);
            #pragma unroll
            for (int ct = 0; ct < 8; ct++) {
                floatx4 acc = {0.f, 0.f, 0.f, 0.f};
                #pragma unroll
                for (int ks = 0; ks < 4; ks++) acc = MFMA(a1[ks], FRAG(P1p, ct, ks, lane), acc);
                float bb = b1[ct * 16 + m];
                #pragma unroll
                for (int reg = 0; reg < 4; reg++)
                    zt[(quad * 4 + reg) * 136 + ct * 16 + m] = f2b(gelu_exact(acc[reg] + bb));
            }
            short8 a2[4];
            #pragma unroll
            for (int ks = 0; ks < 4; ks++)
                a2[ks] = *(const short8*)(zt + m * 136 + ks * 32 + quad * 8);
            #pragma unroll
            for (int ct = 0; ct < 8; ct++) {
                floatx4 acc = {0.f, 0.f, 0.f, 0.f};
                #pragma unroll
                for (int ks = 0; ks < 4; ks++) acc = MFMA(a2[ks], FRAG(P2p, ct, ks, lane), acc);
                float bb = b2[ct * 16 + m];
                #pragma unroll
                for (int reg = 0; reg < 4; reg++)
                    zt[(quad * 4 + reg) * 136 + ct * 16 + m] = f2b(gelu_exact(acc[reg] + bb));
            }
            short8 a3[4];
            #pragma unroll
            for (int ks = 0; ks < 4; ks++)
                a3[ks] = *(const short8*)(zt + m * 136 + ks * 32 + quad * 8);
            #pragma unroll
            for (int ct = 0; ct < 4; ct++) {
                floatx4 acc = {0.f, 0.f, 0.f, 0.f};
                #pragma unroll
                for (int ks = 0; ks < 4; ks++) acc = MFMA(a3[ks], FRAG(P3p, ct, ks, lane), acc);
                float bb = b3[ct * 16 + m];
                #pragma unroll
                for (int reg = 0; reg < 4; reg++)
                    means[(size_t)(r0 + quad * 4 + reg) * 64 + ct * 16 + m] = acc[reg] + bb;
            }
        }
    }
}

// ---------------- launch ----------------

extern "C" void kernel_launch(void* const* d_in, const int* in_sizes, int n_in,
                              void* d_out, int out_size, void* d_ws, size_t ws_size,
                              hipStream_t stream) {
    const float* feat  = (const float*)d_in[0];
    const int*   eidx  = (const int*)d_in[1];
    const float* W_gcn = (const float*)d_in[2];
    const float* b_gcn = (const float*)d_in[3];
    const float* W_sl  = (const float*)d_in[4];
    const float* b_sl  = (const float*)d_in[5];
    const float* W_sr  = (const float*)d_in[6];
    const float* W1    = (const float*)d_in[7];
    const float* b1    = (const float*)d_in[8];
    const float* W2    = (const float*)d_in[9];
    const float* b2    = (const float*)d_in[10];
    const float* W3    = (const float*)d_in[11];
    const float* b3    = (const float*)d_in[12];
    const float* Wv    = (const float*)d_in[13];
    const float* bv    = (const float*)d_in[14];

    int N = in_sizes[0] / 128;
    int E = in_sizes[1] / 2;

    char* ws = (char*)d_ws;
    size_t off = 0;
    auto alloc = [&](size_t bytes) -> void* {
        void* p = ws + off;
        off += (bytes + 255) & ~(size_t)255;
        return p;
    };
    // zero-zone: [bar(16 slots x 32 ints) | cnt(N)] — one memset covers both
    int*   bar     = (int*)alloc((size_t)(512 + N) * 4);
    int*   cnt     = bar + 512;
    size_t zbytes  = (size_t)(512 + N) * 4;
    int*   rank    = (int*)alloc((size_t)E * 4);
    int*   row_ptr = (int*)alloc((size_t)(N + 1) * 4);
    float* dinv    = (float*)alloc((size_t)N * 4);
    int*   col     = (int*)alloc((size_t)E * 4);
    int*   gsums   = (int*)alloc(256 * 4);
    unsigned short* xs   = (unsigned short*)alloc((size_t)N * 128 * 2);
    unsigned short* h1   = (unsigned short*)alloc((size_t)N * 128 * 2);
    unsigned short* mean = (unsigned short*)alloc((size_t)N * 128 * 2);
    unsigned short* Pg   = (unsigned short*)alloc(2048 * 8 * 2);
    unsigned short* Psl  = (unsigned short*)alloc(2048 * 8 * 2);
    unsigned short* Psr  = (unsigned short*)alloc(2048 * 8 * 2);
    unsigned short* P1p  = (unsigned short*)alloc(2048 * 8 * 2);
    unsigned short* P2p  = (unsigned short*)alloc(2048 * 8 * 2);
    unsigned short* P3p  = (unsigned short*)alloc(1024 * 8 * 2);

    float* means  = (float*)d_out;
    float* values = (float*)d_out + (size_t)N * 64;

    hipMemsetAsync(bar, 0, zbytes, stream);

    mega_kernel<<<240, 512, 0, stream>>>(
        feat, eidx, W_gcn, b_gcn, W_sl, b_sl, W_sr,
        W1, b1, W2, b2, W3, b3, Wv, bv,
        bar, cnt, rank, row_ptr, dinv, col, gsums,
        xs, h1, mean, Pg, Psl, Psr, P1p, P2p, P3p,
        means, values, N, E);
}

// Round 7
// 253.682 us; speedup vs baseline: 1.7794x; 1.7794x over previous
//
#include <hip/hip_runtime.h>
#include <math.h>

// N = 20000, E = 640000, IN_DIM = HID = 128, OUT = 64
// Multi-launch pipeline; activations bf16, accumulation fp32 via MFMA 16x16x32.
// Aggregation processes features in two 64-wide halves so the gathered table
// (2.56 MB) is per-XCD-L2 resident (4 MB), instead of 5.12 MB spilling to LLC.

typedef __attribute__((ext_vector_type(8))) short short8;
typedef __attribute__((ext_vector_type(4))) float floatx4;

__device__ __forceinline__ unsigned short f2b(float f) {
    unsigned u = __float_as_uint(f);
    return (unsigned short)((u + 0x7fffu + ((u >> 16) & 1u)) >> 16);
}
__device__ __forceinline__ unsigned pack2(float a, float b) {
    return (unsigned)f2b(a) | ((unsigned)f2b(b) << 16);
}
__device__ __forceinline__ float b2f_lo(unsigned v) { return __uint_as_float(v << 16); }
__device__ __forceinline__ float b2f_hi(unsigned v) { return __uint_as_float(v & 0xffff0000u); }
__device__ __forceinline__ floatx4 MFMA(short8 a, short8 b, floatx4 c) {
    return __builtin_amdgcn_mfma_f32_16x16x32_bf16(a, b, c, 0, 0, 0);
}
__device__ __forceinline__ float gelu_exact(float x) {
    return 0.5f * x * (1.0f + erff(x * 0.70710678118654752440f));
}
#define FRAG(P, ct, ks, lane) (*(const short8*)((P) + (((((ct)*4 + (ks))*64) + (lane)) << 3)))

// ---------------- count (+rank) fused with weight packing ----------------

__global__ __launch_bounds__(256) void count_pack_kernel(
    const int* __restrict__ eidx, int E,
    int* __restrict__ cnt, int* __restrict__ rank,
    const float* Wg, const float* Wsl, const float* Wsr,
    const float* W1, const float* W2, const float* W3,
    unsigned short* Pg, unsigned short* Psl, unsigned short* Psr,
    unsigned short* P1, unsigned short* P2, unsigned short* P3,
    int countBlocks)
{
    if ((int)blockIdx.x < countBlocks) {
        int e = blockIdx.x * 256 + threadIdx.x;
        if (e < E) {
            int d = eidx[E + e];
            rank[e] = atomicAdd(&cnt[d], 1);
        }
        return;
    }
    int t = (blockIdx.x - countBlocks) * 256 + threadIdx.x;
    const float* W; unsigned short* P; int NC = 128; int base;
    if (t < 2048)       { W = Wg;  P = Pg;  base = t; }
    else if (t < 4096)  { W = Wsl; P = Psl; base = t - 2048; }
    else if (t < 6144)  { W = Wsr; P = Psr; base = t - 4096; }
    else if (t < 8192)  { W = W1;  P = P1;  base = t - 6144; }
    else if (t < 10240) { W = W2;  P = P2;  base = t - 8192; }
    else if (t < 11264) { W = W3;  P = P3;  base = t - 10240; NC = 64; }
    else return;
    int l  = base & 63;
    int ks = (base >> 6) & 3;
    int ct = base >> 8;
    int n  = ct * 16 + (l & 15);
    int k0 = ks * 32 + ((l >> 4) << 3);
    short8 v;
    #pragma unroll
    for (int j = 0; j < 8; j++) v[j] = (short)f2b(W[(size_t)(k0 + j) * NC + n]);
    *(short8*)(P + ((size_t)base << 3)) = v;
}

// -------- scan: absolute prefix via decoupled lookback (validated in r4) ----

__global__ __launch_bounds__(256) void scan_kernel(
    const int* __restrict__ cnt, int N,
    int* __restrict__ row_ptr, float* __restrict__ dinv,
    int* __restrict__ gflags, int* __restrict__ gsums)
{
    __shared__ int sh[256];
    __shared__ int s_off;
    int b = blockIdx.x, tid = threadIdx.x;
    int i0 = b * 1024 + tid * 4;
    int v0 = (i0 + 0 < N) ? cnt[i0 + 0] : 0;
    int v1 = (i0 + 1 < N) ? cnt[i0 + 1] : 0;
    int v2 = (i0 + 2 < N) ? cnt[i0 + 2] : 0;
    int v3 = (i0 + 3 < N) ? cnt[i0 + 3] : 0;
    int tot = v0 + v1 + v2 + v3;
    sh[tid] = tot;
    __syncthreads();
    for (int off = 1; off < 256; off <<= 1) {
        int t = (tid >= off) ? sh[tid - off] : 0;
        __syncthreads();
        sh[tid] += t;
        __syncthreads();
    }
    if (tid == 255) {
        gsums[b] = sh[255];
        __hip_atomic_store(&gflags[b], 1, __ATOMIC_RELEASE, __HIP_MEMORY_SCOPE_AGENT);
    }
    if (tid == 0) {
        int off = 0;
        for (int j = 0; j < b; j++) {
            while (__hip_atomic_load(&gflags[j], __ATOMIC_ACQUIRE,
                                     __HIP_MEMORY_SCOPE_AGENT) == 0) {}
            off += gsums[j];
        }
        s_off = off;
    }
    __syncthreads();
    int excl = s_off + sh[tid] - tot;
    if (i0 + 0 < N) { row_ptr[i0 + 0] = excl;                dinv[i0 + 0] = rsqrtf((float)(v0 + 1)); }
    if (i0 + 1 < N) { row_ptr[i0 + 1] = excl + v0;           dinv[i0 + 1] = rsqrtf((float)(v1 + 1)); }
    if (i0 + 2 < N) { row_ptr[i0 + 2] = excl + v0 + v1;      dinv[i0 + 2] = rsqrtf((float)(v2 + 1)); }
    if (i0 + 3 < N) { row_ptr[i0 + 3] = excl + v0 + v1 + v2; dinv[i0 + 3] = rsqrtf((float)(v3 + 1)); }
    if (b == (int)gridDim.x - 1 && tid == 255) row_ptr[N] = s_off + sh[255];
}

// ------- fill (rank-based scatter, nt stores) + GCN GEMM (dinv-scaled) ------

__global__ __launch_bounds__(256) void fill_gemm_kernel(
    const int* __restrict__ eidx, const int* __restrict__ rank,
    const int* __restrict__ row_ptr, int E, int* __restrict__ col,
    const float* __restrict__ feat, const float* __restrict__ dinv,
    const unsigned short* __restrict__ Pg, unsigned short* __restrict__ xs,
    int M, int fillBlocks)
{
    if ((int)blockIdx.x < fillBlocks) {
        int e = blockIdx.x * 256 + threadIdx.x;
        if (e < E) {
            int d = eidx[E + e];
            int pos = row_ptr[d] + rank[e];
            __builtin_nontemporal_store(eidx[e], &col[pos]);
        }
        return;
    }
    // GCN GEMM: wave computes 16 rows x 64 cols of xs = bf16(dinv .* (feat @ Wg))
    int bid = blockIdx.x - fillBlocks;
    int w = bid * 4 + (threadIdx.x >> 6);
    if (w >= (M / 16) * 2) return;
    int lane = threadIdx.x & 63;
    int m = lane & 15, quad = lane >> 4;
    int rt = w >> 1, ch = w & 1;
    const float* arow = feat + (size_t)(rt * 16 + m) * 128;
    short8 a[4];
    #pragma unroll
    for (int ks = 0; ks < 4; ks++) {
        float4 f0 = *(const float4*)(arow + ks * 32 + quad * 8);
        float4 f1 = *(const float4*)(arow + ks * 32 + quad * 8 + 4);
        short8 s;
        s[0] = (short)f2b(f0.x); s[1] = (short)f2b(f0.y);
        s[2] = (short)f2b(f0.z); s[3] = (short)f2b(f0.w);
        s[4] = (short)f2b(f1.x); s[5] = (short)f2b(f1.y);
        s[6] = (short)f2b(f1.z); s[7] = (short)f2b(f1.w);
        a[ks] = s;
    }
    float dvr[4];
    #pragma unroll
    for (int reg = 0; reg < 4; reg++) dvr[reg] = dinv[rt * 16 + quad * 4 + reg];
    #pragma unroll
    for (int ct = 0; ct < 4; ct++) {
        floatx4 acc = {0.f, 0.f, 0.f, 0.f};
        #pragma unroll
        for (int ks = 0; ks < 4; ks++)
            acc = MFMA(a[ks], FRAG(Pg, ch * 4 + ct, ks, lane), acc);
        #pragma unroll
        for (int reg = 0; reg < 4; reg++)
            xs[(size_t)(rt * 16 + quad * 4 + reg) * 128 + (ch * 4 + ct) * 16 + m] =
                f2b(acc[reg] * dvr[reg]);
    }
}

// ---------------- aggregation: feature-halved, 8 groups x 8 lanes -----------
// Per half (64 features = 128 B = 8 lanes x uint4), table = 2.56 MB -> fits
// per-XCD L2. 2 adjacent nodes/wave, 4-deep edge unroll per group.
// GCN:  h1[d] = relu(dinv[d]*(sum xs'[s] + xs'[d]) + b)   (xs' pre-scaled)
// SAGE: mean[d] = (1/max(deg,1)) * sum h1[s]

__device__ __forceinline__ void acc8(float* a, uint4 q) {
    a[0] += b2f_lo(q.x); a[1] += b2f_hi(q.x);
    a[2] += b2f_lo(q.y); a[3] += b2f_hi(q.y);
    a[4] += b2f_lo(q.z); a[5] += b2f_hi(q.z);
    a[6] += b2f_lo(q.w); a[7] += b2f_hi(q.w);
}

template<bool GCN>
__global__ __launch_bounds__(256) void agg_kernel(
    const unsigned short* __restrict__ X, const int* __restrict__ row_ptr,
    const int* __restrict__ col, const float* __restrict__ dinv,
    const float* __restrict__ bias, unsigned short* __restrict__ Y, int N)
{
    int pw = (int)((blockIdx.x * 256 + threadIdx.x) >> 6);
    if (pw * 2 >= N) return;
    int lane = threadIdx.x & 63;
    int t = lane & 7, g = lane >> 3;           // 8 groups of 8 lanes
    const uint4* Xq = (const uint4*)X;         // row = 16 uint4
    int w0 = pw * 2, w1 = w0 + 1;
    int beg0 = row_ptr[w0];
    int mid  = row_ptr[w1];
    int end1 = row_ptr[w1 + 1];

    #pragma unroll
    for (int half = 0; half < 2; half++) {
        const int hoff = half * 8;
        float a0[8] = {0.f,0.f,0.f,0.f,0.f,0.f,0.f,0.f};
        float a1[8] = {0.f,0.f,0.f,0.f,0.f,0.f,0.f,0.f};
        int jb0 = beg0, jb1 = mid;
        // interleaved 32-step: 4 edges/group/node -> 8 gathers in flight
        while (jb0 + 32 <= mid && jb1 + 32 <= end1) {
            int s00 = __builtin_nontemporal_load(&col[jb0 + g]);
            int s01 = __builtin_nontemporal_load(&col[jb0 + 8 + g]);
            int s02 = __builtin_nontemporal_load(&col[jb0 + 16 + g]);
            int s03 = __builtin_nontemporal_load(&col[jb0 + 24 + g]);
            int s10 = __builtin_nontemporal_load(&col[jb1 + g]);
            int s11 = __builtin_nontemporal_load(&col[jb1 + 8 + g]);
            int s12 = __builtin_nontemporal_load(&col[jb1 + 16 + g]);
            int s13 = __builtin_nontemporal_load(&col[jb1 + 24 + g]);
            uint4 q00 = Xq[(size_t)s00 * 16 + hoff + t];
            uint4 q01 = Xq[(size_t)s01 * 16 + hoff + t];
            uint4 q02 = Xq[(size_t)s02 * 16 + hoff + t];
            uint4 q03 = Xq[(size_t)s03 * 16 + hoff + t];
            uint4 q10 = Xq[(size_t)s10 * 16 + hoff + t];
            uint4 q11 = Xq[(size_t)s11 * 16 + hoff + t];
            uint4 q12 = Xq[(size_t)s12 * 16 + hoff + t];
            uint4 q13 = Xq[(size_t)s13 * 16 + hoff + t];
            acc8(a0, q00); acc8(a0, q01); acc8(a0, q02); acc8(a0, q03);
            acc8(a1, q10); acc8(a1, q11); acc8(a1, q12); acc8(a1, q13);
            jb0 += 32; jb1 += 32;
        }
        // drain node 0 then node 1 (8-step, 1 edge/group)
        while (jb0 + 32 <= mid) {
            int s0 = __builtin_nontemporal_load(&col[jb0 + g]);
            int s1 = __builtin_nontemporal_load(&col[jb0 + 8 + g]);
            int s2 = __builtin_nontemporal_load(&col[jb0 + 16 + g]);
            int s3 = __builtin_nontemporal_load(&col[jb0 + 24 + g]);
            uint4 q0 = Xq[(size_t)s0 * 16 + hoff + t];
            uint4 q1 = Xq[(size_t)s1 * 16 + hoff + t];
            uint4 q2 = Xq[(size_t)s2 * 16 + hoff + t];
            uint4 q3 = Xq[(size_t)s3 * 16 + hoff + t];
            acc8(a0, q0); acc8(a0, q1); acc8(a0, q2); acc8(a0, q3);
            jb0 += 32;
        }
        while (jb1 + 32 <= end1) {
            int s0 = __builtin_nontemporal_load(&col[jb1 + g]);
            int s1 = __builtin_nontemporal_load(&col[jb1 + 8 + g]);
            int s2 = __builtin_nontemporal_load(&col[jb1 + 16 + g]);
            int s3 = __builtin_nontemporal_load(&col[jb1 + 24 + g]);
            uint4 q0 = Xq[(size_t)s0 * 16 + hoff + t];
            uint4 q1 = Xq[(size_t)s1 * 16 + hoff + t];
            uint4 q2 = Xq[(size_t)s2 * 16 + hoff + t];
            uint4 q3 = Xq[(size_t)s3 * 16 + hoff + t];
            acc8(a1, q0); acc8(a1, q1); acc8(a1, q2); acc8(a1, q3);
            jb1 += 32;
        }
        for (int j = jb0 + g; j < mid; j += 8) {
            int s = __builtin_nontemporal_load(&col[j]);
            uint4 q = Xq[(size_t)s * 16 + hoff + t];
            acc8(a0, q);
        }
        for (int j = jb1 + g; j < end1; j += 8) {
            int s = __builtin_nontemporal_load(&col[j]);
            uint4 q = Xq[(size_t)s * 16 + hoff + t];
            acc8(a1, q);
        }
        // reduce across the 8 groups
        #pragma unroll
        for (int i = 0; i < 8; i++) {
            a0[i] += __shfl_xor(a0[i], 8);  a1[i] += __shfl_xor(a1[i], 8);
            a0[i] += __shfl_xor(a0[i], 16); a1[i] += __shfl_xor(a1[i], 16);
            a0[i] += __shfl_xor(a0[i], 32); a1[i] += __shfl_xor(a1[i], 32);
        }
        // epilogue: group 0 -> node w0, group 1 -> node w1
        int w = (g == 0) ? w0 : w1;
        float* a = (g == 0) ? a0 : a1;
        int deg = (g == 0) ? (mid - beg0) : (end1 - mid);
        if (g < 2) {
            float out[8];
            if (GCN) {
                uint4 q = Xq[(size_t)w * 16 + hoff + t];  // self loop (pre-scaled)
                acc8(a, q);
                float dw = dinv[w];
                float4 b0 = *(const float4*)(bias + half * 64 + t * 8);
                float4 b1 = *(const float4*)(bias + half * 64 + t * 8 + 4);
                out[0] = fmaxf(fmaf(a[0], dw, b0.x), 0.f);
                out[1] = fmaxf(fmaf(a[1], dw, b0.y), 0.f);
                out[2] = fmaxf(fmaf(a[2], dw, b0.z), 0.f);
                out[3] = fmaxf(fmaf(a[3], dw, b0.w), 0.f);
                out[4] = fmaxf(fmaf(a[4], dw, b1.x), 0.f);
                out[5] = fmaxf(fmaf(a[5], dw, b1.y), 0.f);
                out[6] = fmaxf(fmaf(a[6], dw, b1.z), 0.f);
                out[7] = fmaxf(fmaf(a[7], dw, b1.w), 0.f);
            } else {
                float rc = 1.0f / (float)(deg > 0 ? deg : 1);
                #pragma unroll
                for (int i = 0; i < 8; i++) out[i] = a[i] * rc;
            }
            uint4 r;
            r.x = pack2(out[0], out[1]);
            r.y = pack2(out[2], out[3]);
            r.z = pack2(out[4], out[5]);
            r.w = pack2(out[6], out[7]);
            ((uint4*)Y)[(size_t)w * 16 + hoff + t] = r;
        }
    }
}

// ---------------- fused SAGE + policy MLP + value head ----------------

__global__ __launch_bounds__(256) void sage_mlp_kernel(
    const unsigned short* __restrict__ mean, const unsigned short* __restrict__ h1,
    const unsigned short* __restrict__ Psl, const unsigned short* __restrict__ Psr,
    const float* __restrict__ bsl,
    const unsigned short* __restrict__ P1, const float* __restrict__ b1,
    const unsigned short* __restrict__ P2, const float* __restrict__ b2,
    const unsigned short* __restrict__ P3, const float* __restrict__ b3,
    const float* __restrict__ Wv, const float* __restrict__ bv,
    float* __restrict__ means, float* __restrict__ values, int M)
{
    __shared__ unsigned short z[4][16 * 136];
    int widx = threadIdx.x >> 6, lane = threadIdx.x & 63;
    int w = blockIdx.x * 4 + widx;
    if (w >= M / 16) return;
    int m = lane & 15, quad = lane >> 4;
    unsigned short* zt = &z[widx][0];
    int r0 = w * 16;

    short8 am[4], ar[4];
    #pragma unroll
    for (int ks = 0; ks < 4; ks++) {
        am[ks] = *(const short8*)(mean + (size_t)(r0 + m) * 128 + ks * 32 + quad * 8);
        ar[ks] = *(const short8*)(h1   + (size_t)(r0 + m) * 128 + ks * 32 + quad * 8);
    }

    float vpart[4] = {0.f, 0.f, 0.f, 0.f};
    #pragma unroll
    for (int ct = 0; ct < 8; ct++) {
        floatx4 acc = {0.f, 0.f, 0.f, 0.f};
        #pragma unroll
        for (int ks = 0; ks < 4; ks++) acc = MFMA(am[ks], FRAG(Psl, ct, ks, lane), acc);
        #pragma unroll
        for (int ks = 0; ks < 4; ks++) acc = MFMA(ar[ks], FRAG(Psr, ct, ks, lane), acc);
        float bb = bsl[ct * 16 + m];
        float wv = Wv[ct * 16 + m];
        #pragma unroll
        for (int reg = 0; reg < 4; reg++) {
            float o = fmaxf(acc[reg] + bb, 0.f);
            vpart[reg] = fmaf(o, wv, vpart[reg]);
            zt[(quad * 4 + reg) * 136 + ct * 16 + m] = f2b(o);
        }
    }
    #pragma unroll
    for (int off = 1; off <= 8; off <<= 1) {
        #pragma unroll
        for (int reg = 0; reg < 4; reg++)
            vpart[reg] += __shfl_xor(vpart[reg], off);
    }
    if (m == 0) {
        float bvv = bv[0];
        #pragma unroll
        for (int reg = 0; reg < 4; reg++)
            values[r0 + quad * 4 + reg] = vpart[reg] + bvv;
    }

    short8 a1[4];
    #pragma unroll
    for (int ks = 0; ks < 4; ks++)
        a1[ks] = *(const short8*)(zt + m * 136 + ks * 32 + quad * 8);

    #pragma unroll
    for (int ct = 0; ct < 8; ct++) {
        floatx4 acc = {0.f, 0.f, 0.f, 0.f};
        #pragma unroll
        for (int ks = 0; ks < 4; ks++) acc = MFMA(a1[ks], FRAG(P1, ct, ks, lane), acc);
        float bb = b1[ct * 16 + m];
        #pragma unroll
        for (int reg = 0; reg < 4; reg++)
            zt[(quad * 4 + reg) * 136 + ct * 16 + m] = f2b(gelu_exact(acc[reg] + bb));
    }
    short8 a2[4];
    #pragma unroll
    for (int ks = 0; ks < 4; ks++)
        a2[ks] = *(const short8*)(zt + m * 136 + ks * 32 + quad * 8);

    #pragma unroll
    for (int ct = 0; ct < 8; ct++) {
        floatx4 acc = {0.f, 0.f, 0.f, 0.f};
        #pragma unroll
        for (int ks = 0; ks < 4; ks++) acc = MFMA(a2[ks], FRAG(P2, ct, ks, lane), acc);
        float bb = b2[ct * 16 + m];
        #pragma unroll
        for (int reg = 0; reg < 4; reg++)
            zt[(quad * 4 + reg) * 136 + ct * 16 + m] = f2b(gelu_exact(acc[reg] + bb));
    }
    short8 a3[4];
    #pragma unroll
    for (int ks = 0; ks < 4; ks++)
        a3[ks] = *(const short8*)(zt + m * 136 + ks * 32 + quad * 8);

    #pragma unroll
    for (int ct = 0; ct < 4; ct++) {
        floatx4 acc = {0.f, 0.f, 0.f, 0.f};
        #pragma unroll
        for (int ks = 0; ks < 4; ks++) acc = MFMA(a3[ks], FRAG(P3, ct, ks, lane), acc);
        float bb = b3[ct * 16 + m];
        #pragma unroll
        for (int reg = 0; reg < 4; reg++)
            means[(size_t)(r0 + quad * 4 + reg) * 64 + ct * 16 + m] = acc[reg] + bb;
    }
}

// ---------------- launch ----------------

extern "C" void kernel_launch(void* const* d_in, const int* in_sizes, int n_in,
                              void* d_out, int out_size, void* d_ws, size_t ws_size,
                              hipStream_t stream) {
    const float* feat  = (const float*)d_in[0];
    const int*   eidx  = (const int*)d_in[1];
    const float* W_gcn = (const float*)d_in[2];
    const float* b_gcn = (const float*)d_in[3];
    const float* W_sl  = (const float*)d_in[4];
    const float* b_sl  = (const float*)d_in[5];
    const float* W_sr  = (const float*)d_in[6];
    const float* W1    = (const float*)d_in[7];
    const float* b1    = (const float*)d_in[8];
    const float* W2    = (const float*)d_in[9];
    const float* b2    = (const float*)d_in[10];
    const float* W3    = (const float*)d_in[11];
    const float* b3    = (const float*)d_in[12];
    const float* Wv    = (const float*)d_in[13];
    const float* bv    = (const float*)d_in[14];

    const int N = in_sizes[0] / 128;
    const int E = in_sizes[1] / 2;

    char* ws = (char*)d_ws;
    size_t off = 0;
    auto alloc = [&](size_t bytes) -> void* {
        void* p = ws + off;
        off += (bytes + 255) & ~(size_t)255;
        return p;
    };
    // zero-zone: [gflags(64) | cnt(N)] — one memset covers both
    int*   gflags  = (int*)alloc((size_t)(64 + N) * 4);
    int*   cnt     = gflags + 64;
    size_t zbytes  = (size_t)(64 + N) * 4;
    int*   gsums   = (int*)alloc(64 * 4);
    int*   rank    = (int*)alloc((size_t)E * 4);
    int*   row_ptr = (int*)alloc((size_t)(N + 1) * 4);
    float* dinv    = (float*)alloc((size_t)N * 4);
    int*   col     = (int*)alloc((size_t)E * 4);
    unsigned short* xs   = (unsigned short*)alloc((size_t)N * 128 * 2);
    unsigned short* h1   = (unsigned short*)alloc((size_t)N * 128 * 2);
    unsigned short* mean = (unsigned short*)alloc((size_t)N * 128 * 2);
    unsigned short* Pg   = (unsigned short*)alloc(2048 * 8 * 2);
    unsigned short* Psl  = (unsigned short*)alloc(2048 * 8 * 2);
    unsigned short* Psr  = (unsigned short*)alloc(2048 * 8 * 2);
    unsigned short* P1p  = (unsigned short*)alloc(2048 * 8 * 2);
    unsigned short* P2p  = (unsigned short*)alloc(2048 * 8 * 2);
    unsigned short* P3p  = (unsigned short*)alloc(1024 * 8 * 2);

    hipMemsetAsync(gflags, 0, zbytes, stream);

    const int countBlocks = (E + 255) / 256;          // 2500
    const int packBlocks  = (11264 + 255) / 256;      // 44
    count_pack_kernel<<<countBlocks + packBlocks, 256, 0, stream>>>(
        eidx, E, cnt, rank, W_gcn, W_sl, W_sr, W1, W2, W3,
        Pg, Psl, Psr, P1p, P2p, P3p, countBlocks);

    const int NB = (N + 1023) / 1024;                 // 20
    scan_kernel<<<NB, 256, 0, stream>>>(cnt, N, row_ptr, dinv, gflags, gsums);

    const int fillBlocks = (E + 255) / 256;           // 2500
    const int gemmBlocks = ((N / 16) * 2 + 3) / 4;    // 625
    fill_gemm_kernel<<<fillBlocks + gemmBlocks, 256, 0, stream>>>(
        eidx, rank, row_ptr, E, col, feat, dinv, Pg, xs, N, fillBlocks);

    const int agrid = ((N + 1) / 2 + 3) / 4;          // 2 nodes/wave, 4 waves/block
    agg_kernel<true><<<agrid, 256, 0, stream>>>(xs, row_ptr, col, dinv, b_gcn, h1, N);
    agg_kernel<false><<<agrid, 256, 0, stream>>>(h1, row_ptr, col, dinv, nullptr, mean, N);

    sage_mlp_kernel<<<(N / 16 + 3) / 4, 256, 0, stream>>>(
        mean, h1, Psl, Psr, b_sl, P1p, b1, P2p, b2, P3p, b3, Wv, bv,
        (float*)d_out, (float*)d_out + (size_t)N * 64, N);
}

// Round 8
// 203.036 us; speedup vs baseline: 2.2233x; 1.2494x over previous
//
#include <hip/hip_runtime.h>
#include <math.h>

// N = 20000, E = 640000, IN_DIM = HID = 128, OUT = 64
// Multi-launch pipeline; activations bf16, accumulation fp32 via MFMA 16x16x32.

typedef __attribute__((ext_vector_type(8))) short short8;
typedef __attribute__((ext_vector_type(4))) float floatx4;

__device__ __forceinline__ unsigned short f2b(float f) {
    unsigned u = __float_as_uint(f);
    return (unsigned short)((u + 0x7fffu + ((u >> 16) & 1u)) >> 16);
}
__device__ __forceinline__ unsigned pack2(float a, float b) {
    return (unsigned)f2b(a) | ((unsigned)f2b(b) << 16);
}
__device__ __forceinline__ float b2f_lo(unsigned v) { return __uint_as_float(v << 16); }
__device__ __forceinline__ float b2f_hi(unsigned v) { return __uint_as_float(v & 0xffff0000u); }
__device__ __forceinline__ floatx4 MFMA(short8 a, short8 b, floatx4 c) {
    return __builtin_amdgcn_mfma_f32_16x16x32_bf16(a, b, c, 0, 0, 0);
}
__device__ __forceinline__ float gelu_exact(float x) {
    return 0.5f * x * (1.0f + erff(x * 0.70710678118654752440f));
}
#define FRAG(P, ct, ks, lane) (*(const short8*)((P) + (((((ct)*4 + (ks))*64) + (lane)) << 3)))

// ---------------- count (+rank) fused with weight packing ----------------

__global__ __launch_bounds__(256) void count_pack_kernel(
    const int* __restrict__ eidx, int E,
    int* __restrict__ cnt, int* __restrict__ rank,
    const float* Wg, const float* Wsl, const float* Wsr,
    const float* W1, const float* W2, const float* W3,
    unsigned short* Pg, unsigned short* Psl, unsigned short* Psr,
    unsigned short* P1, unsigned short* P2, unsigned short* P3,
    int countBlocks)
{
    if ((int)blockIdx.x < countBlocks) {
        int e = blockIdx.x * 256 + threadIdx.x;
        if (e < E) {
            int d = eidx[E + e];
            rank[e] = atomicAdd(&cnt[d], 1);
        }
        return;
    }
    int t = (blockIdx.x - countBlocks) * 256 + threadIdx.x;
    const float* W; unsigned short* P; int NC = 128; int base;
    if (t < 2048)       { W = Wg;  P = Pg;  base = t; }
    else if (t < 4096)  { W = Wsl; P = Psl; base = t - 2048; }
    else if (t < 6144)  { W = Wsr; P = Psr; base = t - 4096; }
    else if (t < 8192)  { W = W1;  P = P1;  base = t - 6144; }
    else if (t < 10240) { W = W2;  P = P2;  base = t - 8192; }
    else if (t < 11264) { W = W3;  P = P3;  base = t - 10240; NC = 64; }
    else return;
    int l  = base & 63;
    int ks = (base >> 6) & 3;
    int ct = base >> 8;
    int n  = ct * 16 + (l & 15);
    int k0 = ks * 32 + ((l >> 4) << 3);
    short8 v;
    #pragma unroll
    for (int j = 0; j < 8; j++) v[j] = (short)f2b(W[(size_t)(k0 + j) * NC + n]);
    *(short8*)(P + ((size_t)base << 3)) = v;
}

// -------- scan: absolute prefix via decoupled lookback (validated in r4) ----

__global__ __launch_bounds__(256) void scan_kernel(
    const int* __restrict__ cnt, int N,
    int* __restrict__ row_ptr, float* __restrict__ dinv,
    int* __restrict__ gflags, int* __restrict__ gsums)
{
    __shared__ int sh[256];
    __shared__ int s_off;
    int b = blockIdx.x, tid = threadIdx.x;
    int i0 = b * 1024 + tid * 4;
    int v0 = (i0 + 0 < N) ? cnt[i0 + 0] : 0;
    int v1 = (i0 + 1 < N) ? cnt[i0 + 1] : 0;
    int v2 = (i0 + 2 < N) ? cnt[i0 + 2] : 0;
    int v3 = (i0 + 3 < N) ? cnt[i0 + 3] : 0;
    int tot = v0 + v1 + v2 + v3;
    sh[tid] = tot;
    __syncthreads();
    for (int off = 1; off < 256; off <<= 1) {
        int t = (tid >= off) ? sh[tid - off] : 0;
        __syncthreads();
        sh[tid] += t;
        __syncthreads();
    }
    if (tid == 255) {
        gsums[b] = sh[255];
        __hip_atomic_store(&gflags[b], 1, __ATOMIC_RELEASE, __HIP_MEMORY_SCOPE_AGENT);
    }
    if (tid == 0) {
        int off = 0;
        for (int j = 0; j < b; j++) {
            while (__hip_atomic_load(&gflags[j], __ATOMIC_ACQUIRE,
                                     __HIP_MEMORY_SCOPE_AGENT) == 0) {}
            off += gsums[j];
        }
        s_off = off;
    }
    __syncthreads();
    int excl = s_off + sh[tid] - tot;
    if (i0 + 0 < N) { row_ptr[i0 + 0] = excl;                dinv[i0 + 0] = rsqrtf((float)(v0 + 1)); }
    if (i0 + 1 < N) { row_ptr[i0 + 1] = excl + v0;           dinv[i0 + 1] = rsqrtf((float)(v1 + 1)); }
    if (i0 + 2 < N) { row_ptr[i0 + 2] = excl + v0 + v1;      dinv[i0 + 2] = rsqrtf((float)(v2 + 1)); }
    if (i0 + 3 < N) { row_ptr[i0 + 3] = excl + v0 + v1 + v2; dinv[i0 + 3] = rsqrtf((float)(v3 + 1)); }
    if (b == (int)gridDim.x - 1 && tid == 255) row_ptr[N] = s_off + sh[255];
}

// ------- fill (rank-based scatter) + GCN GEMM (dinv-scaled epilogue) --------

__global__ __launch_bounds__(256) void fill_gemm_kernel(
    const int* __restrict__ eidx, const int* __restrict__ rank,
    const int* __restrict__ row_ptr, int E, int* __restrict__ col,
    const float* __restrict__ feat, const float* __restrict__ dinv,
    const unsigned short* __restrict__ Pg, unsigned short* __restrict__ xs,
    int M, int fillBlocks)
{
    if ((int)blockIdx.x < fillBlocks) {
        int e = blockIdx.x * 256 + threadIdx.x;
        if (e < E) {
            int d = eidx[E + e];
            col[row_ptr[d] + rank[e]] = eidx[e];
        }
        return;
    }
    // GCN GEMM: wave computes 16 rows x 64 cols of xs = bf16(dinv .* (feat @ Wg))
    int bid = blockIdx.x - fillBlocks;
    int w = bid * 4 + (threadIdx.x >> 6);
    if (w >= (M / 16) * 2) return;
    int lane = threadIdx.x & 63;
    int m = lane & 15, quad = lane >> 4;
    int rt = w >> 1, ch = w & 1;
    const float* arow = feat + (size_t)(rt * 16 + m) * 128;
    short8 a[4];
    #pragma unroll
    for (int ks = 0; ks < 4; ks++) {
        float4 f0 = *(const float4*)(arow + ks * 32 + quad * 8);
        float4 f1 = *(const float4*)(arow + ks * 32 + quad * 8 + 4);
        short8 s;
        s[0] = (short)f2b(f0.x); s[1] = (short)f2b(f0.y);
        s[2] = (short)f2b(f0.z); s[3] = (short)f2b(f0.w);
        s[4] = (short)f2b(f1.x); s[5] = (short)f2b(f1.y);
        s[6] = (short)f2b(f1.z); s[7] = (short)f2b(f1.w);
        a[ks] = s;
    }
    float dvr[4];
    #pragma unroll
    for (int reg = 0; reg < 4; reg++) dvr[reg] = dinv[rt * 16 + quad * 4 + reg];
    #pragma unroll
    for (int ct = 0; ct < 4; ct++) {
        floatx4 acc = {0.f, 0.f, 0.f, 0.f};
        #pragma unroll
        for (int ks = 0; ks < 4; ks++)
            acc = MFMA(a[ks], FRAG(Pg, ch * 4 + ct, ks, lane), acc);
        #pragma unroll
        for (int reg = 0; reg < 4; reg++)
            xs[(size_t)(rt * 16 + quad * 4 + reg) * 128 + (ch * 4 + ct) * 16 + m] =
                f2b(acc[reg] * dvr[reg]);
    }
}

// ---------------- aggregation: 2 adjacent nodes/wave, 16-lane groups --------
// GCN:  h1[d] = relu(dinv[d]*(sum xs'[s] + xs'[d]) + b)   (xs' pre-scaled)
// SAGE: mean[d] = (1/max(deg,1)) * sum h1[s]

__device__ __forceinline__ void acc8(float* a, uint4 q) {
    a[0] += b2f_lo(q.x); a[1] += b2f_hi(q.x);
    a[2] += b2f_lo(q.y); a[3] += b2f_hi(q.y);
    a[4] += b2f_lo(q.z); a[5] += b2f_hi(q.z);
    a[6] += b2f_lo(q.w); a[7] += b2f_hi(q.w);
}
__device__ __forceinline__ void step16(const uint4* Xq, const int* __restrict__ col,
                                       int jb, int g, int t, float* acc) {
    int s0 = col[jb + g];
    int s1 = col[jb + 4 + g];
    int s2 = col[jb + 8 + g];
    int s3 = col[jb + 12 + g];
    uint4 q0 = Xq[(size_t)s0 * 16 + t];
    uint4 q1 = Xq[(size_t)s1 * 16 + t];
    uint4 q2 = Xq[(size_t)s2 * 16 + t];
    uint4 q3 = Xq[(size_t)s3 * 16 + t];
    acc8(acc, q0); acc8(acc, q1); acc8(acc, q2); acc8(acc, q3);
}

template<bool GCN>
__global__ __launch_bounds__(256) void agg_kernel(
    const unsigned short* __restrict__ X, const int* __restrict__ row_ptr,
    const int* __restrict__ col, const float* __restrict__ dinv,
    const float* __restrict__ bias, unsigned short* __restrict__ Y, int N)
{
    int pw = (int)((blockIdx.x * 256 + threadIdx.x) >> 6);
    if (pw * 2 >= N) return;
    int lane = threadIdx.x & 63;
    int g = lane >> 4, t = lane & 15;
    const uint4* Xq = (const uint4*)X;
    int w0 = pw * 2, w1 = w0 + 1;
    int beg0 = row_ptr[w0];
    int mid  = row_ptr[w1];
    int end1 = row_ptr[w1 + 1];
    float acc0[8] = {0.f,0.f,0.f,0.f,0.f,0.f,0.f,0.f};
    float acc1[8] = {0.f,0.f,0.f,0.f,0.f,0.f,0.f,0.f};
    int jb0 = beg0, jb1 = mid;
    while (jb0 + 16 <= mid && jb1 + 16 <= end1) {
        step16(Xq, col, jb0, g, t, acc0);
        step16(Xq, col, jb1, g, t, acc1);
        jb0 += 16; jb1 += 16;
    }
    while (jb0 + 16 <= mid)  { step16(Xq, col, jb0, g, t, acc0); jb0 += 16; }
    while (jb1 + 16 <= end1) { step16(Xq, col, jb1, g, t, acc1); jb1 += 16; }
    for (int j = jb0 + g; j < mid; j += 4) {
        int s = col[j];
        uint4 q = Xq[(size_t)s * 16 + t];
        acc8(acc0, q);
    }
    for (int j = jb1 + g; j < end1; j += 4) {
        int s = col[j];
        uint4 q = Xq[(size_t)s * 16 + t];
        acc8(acc1, q);
    }
    #pragma unroll
    for (int i = 0; i < 8; i++) {
        acc0[i] += __shfl_xor(acc0[i], 16); acc0[i] += __shfl_xor(acc0[i], 32);
        acc1[i] += __shfl_xor(acc1[i], 16); acc1[i] += __shfl_xor(acc1[i], 32);
    }
    int w = (g == 1) ? w1 : w0;
    float* a = (g == 1) ? acc1 : acc0;
    int deg = (g == 1) ? (end1 - mid) : (mid - beg0);
    if (g < 2) {
        float out[8];
        if (GCN) {
            uint4 q = Xq[(size_t)w * 16 + t];  // self loop (pre-scaled row)
            acc8(a, q);
            float dw = dinv[w];
            float4 b0 = *(const float4*)(bias + t * 8);
            float4 b1 = *(const float4*)(bias + t * 8 + 4);
            out[0] = fmaxf(fmaf(a[0], dw, b0.x), 0.f);
            out[1] = fmaxf(fmaf(a[1], dw, b0.y), 0.f);
            out[2] = fmaxf(fmaf(a[2], dw, b0.z), 0.f);
            out[3] = fmaxf(fmaf(a[3], dw, b0.w), 0.f);
            out[4] = fmaxf(fmaf(a[4], dw, b1.x), 0.f);
            out[5] = fmaxf(fmaf(a[5], dw, b1.y), 0.f);
            out[6] = fmaxf(fmaf(a[6], dw, b1.z), 0.f);
            out[7] = fmaxf(fmaf(a[7], dw, b1.w), 0.f);
        } else {
            float rc = 1.0f / (float)(deg > 0 ? deg : 1);
            #pragma unroll
            for (int i = 0; i < 8; i++) out[i] = a[i] * rc;
        }
        uint4 r;
        r.x = pack2(out[0], out[1]);
        r.y = pack2(out[2], out[3]);
        r.z = pack2(out[4], out[5]);
        r.w = pack2(out[6], out[7]);
        ((uint4*)Y)[(size_t)w * 16 + t] = r;
    }
}

// ------- fused SAGE + policy MLP + value head: block-cooperative ct-split ---
// One 16-row tile per block; 4 waves split the 8 output col-tiles (2 each,
// 1 each for the 64-col layer 3). Ping-pong LDS between layers.

__global__ __launch_bounds__(256) void sage_mlp_kernel(
    const unsigned short* __restrict__ mean, const unsigned short* __restrict__ h1,
    const unsigned short* __restrict__ Psl, const unsigned short* __restrict__ Psr,
    const float* __restrict__ bsl,
    const unsigned short* __restrict__ P1, const float* __restrict__ b1,
    const unsigned short* __restrict__ P2, const float* __restrict__ b2,
    const unsigned short* __restrict__ P3, const float* __restrict__ b3,
    const float* __restrict__ Wv, const float* __restrict__ bv,
    float* __restrict__ means, float* __restrict__ values, int M)
{
    __shared__ unsigned short z[2][16 * 136];
    __shared__ float vs[4][16];
    int widx = threadIdx.x >> 6, lane = threadIdx.x & 63;
    int m = lane & 15, quad = lane >> 4;
    int r0 = blockIdx.x * 16;

    short8 am[4], ar[4];
    #pragma unroll
    for (int ks = 0; ks < 4; ks++) {
        am[ks] = *(const short8*)(mean + (size_t)(r0 + m) * 128 + ks * 32 + quad * 8);
        ar[ks] = *(const short8*)(h1   + (size_t)(r0 + m) * 128 + ks * 32 + quad * 8);
    }

    // SAGE layer: each wave does ct = 2*widx, 2*widx+1 -> z[0]; value partials
    float vpart[4] = {0.f, 0.f, 0.f, 0.f};
    #pragma unroll
    for (int i = 0; i < 2; i++) {
        int ct = widx * 2 + i;
        floatx4 acc = {0.f, 0.f, 0.f, 0.f};
        #pragma unroll
        for (int ks = 0; ks < 4; ks++) acc = MFMA(am[ks], FRAG(Psl, ct, ks, lane), acc);
        #pragma unroll
        for (int ks = 0; ks < 4; ks++) acc = MFMA(ar[ks], FRAG(Psr, ct, ks, lane), acc);
        float bb = bsl[ct * 16 + m];
        float wv = Wv[ct * 16 + m];
        #pragma unroll
        for (int reg = 0; reg < 4; reg++) {
            float o = fmaxf(acc[reg] + bb, 0.f);
            vpart[reg] = fmaf(o, wv, vpart[reg]);
            z[0][(quad * 4 + reg) * 136 + ct * 16 + m] = f2b(o);
        }
    }
    #pragma unroll
    for (int off = 1; off <= 8; off <<= 1) {
        #pragma unroll
        for (int reg = 0; reg < 4; reg++)
            vpart[reg] += __shfl_xor(vpart[reg], off);
    }
    if (m == 0) {
        #pragma unroll
        for (int reg = 0; reg < 4; reg++) vs[widx][quad * 4 + reg] = vpart[reg];
    }
    __syncthreads();
    if (widx == 0 && lane < 16)
        values[r0 + lane] = vs[0][lane] + vs[1][lane] + vs[2][lane] + vs[3][lane] + bv[0];

    // layer 1: z[0] -> z[1]
    short8 a1[4];
    #pragma unroll
    for (int ks = 0; ks < 4; ks++)
        a1[ks] = *(const short8*)(&z[0][m * 136 + ks * 32 + quad * 8]);
    #pragma unroll
    for (int i = 0; i < 2; i++) {
        int ct = widx * 2 + i;
        floatx4 acc = {0.f, 0.f, 0.f, 0.f};
        #pragma unroll
        for (int ks = 0; ks < 4; ks++) acc = MFMA(a1[ks], FRAG(P1, ct, ks, lane), acc);
        float bb = b1[ct * 16 + m];
        #pragma unroll
        for (int reg = 0; reg < 4; reg++)
            z[1][(quad * 4 + reg) * 136 + ct * 16 + m] = f2b(gelu_exact(acc[reg] + bb));
    }
    __syncthreads();

    // layer 2: z[1] -> z[0]
    short8 a2[4];
    #pragma unroll
    for (int ks = 0; ks < 4; ks++)
        a2[ks] = *(const short8*)(&z[1][m * 136 + ks * 32 + quad * 8]);
    __syncthreads();   // all reads of z[0] (layer-1 inputs) done before rewrite
    #pragma unroll
    for (int i = 0; i < 2; i++) {
        int ct = widx * 2 + i;
        floatx4 acc = {0.f, 0.f, 0.f, 0.f};
        #pragma unroll
        for (int ks = 0; ks < 4; ks++) acc = MFMA(a2[ks], FRAG(P2, ct, ks, lane), acc);
        float bb = b2[ct * 16 + m];
        #pragma unroll
        for (int reg = 0; reg < 4; reg++)
            z[0][(quad * 4 + reg) * 136 + ct * 16 + m] = f2b(gelu_exact(acc[reg] + bb));
    }
    __syncthreads();

    // layer 3: z[0] -> means (64 cols, 1 ct per wave)
    short8 a3[4];
    #pragma unroll
    for (int ks = 0; ks < 4; ks++)
        a3[ks] = *(const short8*)(&z[0][m * 136 + ks * 32 + quad * 8]);
    {
        int ct = widx;
        floatx4 acc = {0.f, 0.f, 0.f, 0.f};
        #pragma unroll
        for (int ks = 0; ks < 4; ks++) acc = MFMA(a3[ks], FRAG(P3, ct, ks, lane), acc);
        float bb = b3[ct * 16 + m];
        #pragma unroll
        for (int reg = 0; reg < 4; reg++)
            means[(size_t)(r0 + quad * 4 + reg) * 64 + ct * 16 + m] = acc[reg] + bb;
    }
}

// ---------------- launch ----------------

extern "C" void kernel_launch(void* const* d_in, const int* in_sizes, int n_in,
                              void* d_out, int out_size, void* d_ws, size_t ws_size,
                              hipStream_t stream) {
    const float* feat  = (const float*)d_in[0];
    const int*   eidx  = (const int*)d_in[1];
    const float* W_gcn = (const float*)d_in[2];
    const float* b_gcn = (const float*)d_in[3];
    const float* W_sl  = (const float*)d_in[4];
    const float* b_sl  = (const float*)d_in[5];
    const float* W_sr  = (const float*)d_in[6];
    const float* W1    = (const float*)d_in[7];
    const float* b1    = (const float*)d_in[8];
    const float* W2    = (const float*)d_in[9];
    const float* b2    = (const float*)d_in[10];
    const float* W3    = (const float*)d_in[11];
    const float* b3    = (const float*)d_in[12];
    const float* Wv    = (const float*)d_in[13];
    const float* bv    = (const float*)d_in[14];

    const int N = in_sizes[0] / 128;
    const int E = in_sizes[1] / 2;

    char* ws = (char*)d_ws;
    size_t off = 0;
    auto alloc = [&](size_t bytes) -> void* {
        void* p = ws + off;
        off += (bytes + 255) & ~(size_t)255;
        return p;
    };
    // zero-zone: [gflags(64) | cnt(N)] — one memset covers both
    int*   gflags  = (int*)alloc((size_t)(64 + N) * 4);
    int*   cnt     = gflags + 64;
    size_t zbytes  = (size_t)(64 + N) * 4;
    int*   gsums   = (int*)alloc(64 * 4);
    int*   rank    = (int*)alloc((size_t)E * 4);
    int*   row_ptr = (int*)alloc((size_t)(N + 1) * 4);
    float* dinv    = (float*)alloc((size_t)N * 4);
    int*   col     = (int*)alloc((size_t)E * 4);
    unsigned short* xs   = (unsigned short*)alloc((size_t)N * 128 * 2);
    unsigned short* h1   = (unsigned short*)alloc((size_t)N * 128 * 2);
    unsigned short* mean = (unsigned short*)alloc((size_t)N * 128 * 2);
    unsigned short* Pg   = (unsigned short*)alloc(2048 * 8 * 2);
    unsigned short* Psl  = (unsigned short*)alloc(2048 * 8 * 2);
    unsigned short* Psr  = (unsigned short*)alloc(2048 * 8 * 2);
    unsigned short* P1p  = (unsigned short*)alloc(2048 * 8 * 2);
    unsigned short* P2p  = (unsigned short*)alloc(2048 * 8 * 2);
    unsigned short* P3p  = (unsigned short*)alloc(1024 * 8 * 2);

    hipMemsetAsync(gflags, 0, zbytes, stream);

    const int countBlocks = (E + 255) / 256;          // 2500
    const int packBlocks  = (11264 + 255) / 256;      // 44
    count_pack_kernel<<<countBlocks + packBlocks, 256, 0, stream>>>(
        eidx, E, cnt, rank, W_gcn, W_sl, W_sr, W1, W2, W3,
        Pg, Psl, Psr, P1p, P2p, P3p, countBlocks);

    const int NB = (N + 1023) / 1024;                 // 20
    scan_kernel<<<NB, 256, 0, stream>>>(cnt, N, row_ptr, dinv, gflags, gsums);

    const int fillBlocks = (E + 255) / 256;           // 2500
    const int gemmBlocks = ((N / 16) * 2 + 3) / 4;    // 625
    fill_gemm_kernel<<<fillBlocks + gemmBlocks, 256, 0, stream>>>(
        eidx, rank, row_ptr, E, col, feat, dinv, Pg, xs, N, fillBlocks);

    const int agrid = (((N + 1) / 2) + 3) / 4;        // 2 nodes/wave, 4 waves/block
    agg_kernel<true><<<agrid, 256, 0, stream>>>(xs, row_ptr, col, dinv, b_gcn, h1, N);
    agg_kernel<false><<<agrid, 256, 0, stream>>>(h1, row_ptr, col, dinv, nullptr, mean, N);

    sage_mlp_kernel<<<N / 16, 256, 0, stream>>>(
        mean, h1, Psl, Psr, b_sl, P1p, b1, P2p, b2, P3p, b3, Wv, bv,
        (float*)d_out, (float*)d_out + (size_t)N * 64, N);
}